// Round 1
// baseline (161.098 us; speedup 1.0000x reference)
//
#include <hip/hip_runtime.h>
#include <hip/hip_bf16.h>

// NodeToGlobal: per-graph segment {mean,min,max,std} over sorted batch ids,
// concat -> [G, 4D] -> @ W [4D, Gdim] + b.
// N=500000, D=256, G=8192, 4D=1024, Gdim=256.

#define DIM 256
#define NG 8192
#define KD 1024   // 4*DIM
#define NOUT 256  // g_dim

typedef __attribute__((ext_vector_type(8))) short bf16x8;
typedef __attribute__((ext_vector_type(4))) float f32x4;

__device__ __forceinline__ unsigned short f2bf(float x) {
    // round-to-nearest-even fp32 -> bf16 (finite inputs only)
    unsigned int u = __float_as_uint(x);
    u += 0x7fffu + ((u >> 16) & 1u);
    return (unsigned short)(u >> 16);
}

// offs[g] = lower_bound(batch, g); offs[NG] = N. Handles int32 or int64 batch.
__global__ void find_offsets_kernel(const int* __restrict__ batch, int N,
                                    int* __restrict__ offs) {
    int g = blockIdx.x * blockDim.x + threadIdx.x;
    if (g > NG) return;
    // int64 detection: word[N-1] is the hi-word of element (N-1)/2 when batch is
    // int64 (== 0 since values < 8192); for int32 it's the max batch id (~8191).
    bool is64 = (batch[N - 1] == 0);
    if (g == NG) { offs[NG] = N; return; }
    int lo = 0, hi = N;
    while (lo < hi) {
        int mid = (lo + hi) >> 1;
        int v = is64 ? batch[2 * mid] : batch[mid];
        if (v < g) lo = mid + 1; else hi = mid;
    }
    offs[g] = lo;
}

// WT[n][k] = bf16(W[k][n]);  W: [1024,256] f32, WT: [256][1024] bf16
__global__ __launch_bounds__(256) void wt_kernel(const float* __restrict__ W,
                                                 unsigned short* __restrict__ WT) {
    int idx = blockIdx.x * 256 + threadIdx.x;   // 0 .. 256*1024-1
    int n = idx >> 10;
    int k = idx & 1023;
    WT[idx] = f2bf(W[k * NOUT + n]);
}

// One wave per graph. Thread (lane) owns dims [4*lane, 4*lane+4). Coalesced
// float4 loads: a wave reads one full 1 KB row per instruction.
__global__ __launch_bounds__(256) void stats_kernel(const float* __restrict__ h,
                                                    const int* __restrict__ offs,
                                                    unsigned short* __restrict__ hc) {
    const int wave = threadIdx.x >> 6;
    const int lane = threadIdx.x & 63;
    const int g = (blockIdx.x << 2) + wave;
    const int start = offs[g];
    const int end = offs[g + 1];

    float s[4] = {0.f, 0.f, 0.f, 0.f};
    float q[4] = {0.f, 0.f, 0.f, 0.f};
    float mn[4] = {INFINITY, INFINITY, INFINITY, INFINITY};
    float mx[4] = {-INFINITY, -INFINITY, -INFINITY, -INFINITY};

    const float4* __restrict__ hv = (const float4*)h;  // 64 float4 per row
    int r = start;
    for (; r + 2 <= end; r += 2) {
        float4 a = hv[(size_t)r * 64 + lane];
        float4 b = hv[(size_t)(r + 1) * 64 + lane];
        float av[4] = {a.x, a.y, a.z, a.w};
        float bv[4] = {b.x, b.y, b.z, b.w};
#pragma unroll
        for (int i = 0; i < 4; ++i) {
            s[i] += av[i]; q[i] = fmaf(av[i], av[i], q[i]);
            mn[i] = fminf(mn[i], av[i]); mx[i] = fmaxf(mx[i], av[i]);
            s[i] += bv[i]; q[i] = fmaf(bv[i], bv[i], q[i]);
            mn[i] = fminf(mn[i], bv[i]); mx[i] = fmaxf(mx[i], bv[i]);
        }
    }
    if (r < end) {
        float4 a = hv[(size_t)r * 64 + lane];
        float av[4] = {a.x, a.y, a.z, a.w};
#pragma unroll
        for (int i = 0; i < 4; ++i) {
            s[i] += av[i]; q[i] = fmaf(av[i], av[i], q[i]);
            mn[i] = fminf(mn[i], av[i]); mx[i] = fmaxf(mx[i], av[i]);
        }
    }

    const int cnt = end - start;
    const float cf = (float)cnt;
    const float inv = cnt > 0 ? 1.f / cf : 0.f;
    const float invm1 = 1.f / fmaxf(cf - 1.f, 1.f);
    float mean[4], sd[4];
#pragma unroll
    for (int i = 0; i < 4; ++i) {
        mean[i] = s[i] * inv;                              // 0 when empty
        float var = (q[i] - mean[i] * s[i]) * invm1;       // unbiased
        sd[i] = sqrtf(fmaxf(var, 0.f));
        if (cnt == 0) { mn[i] = 0.f; mx[i] = 0.f; }
    }

    ushort4* ob = (ushort4*)hc + (size_t)g * 256;  // 1024 bf16 = 256 ushort4 per row
    ob[lane]        = make_ushort4(f2bf(mean[0]), f2bf(mean[1]), f2bf(mean[2]), f2bf(mean[3]));
    ob[64 + lane]   = make_ushort4(f2bf(mn[0]),   f2bf(mn[1]),   f2bf(mn[2]),   f2bf(mn[3]));
    ob[128 + lane]  = make_ushort4(f2bf(mx[0]),   f2bf(mx[1]),   f2bf(mx[2]),   f2bf(mx[3]));
    ob[192 + lane]  = make_ushort4(f2bf(sd[0]),   f2bf(sd[1]),   f2bf(sd[2]),   f2bf(sd[3]));
}

// C[8192,256] = A(bf16)[8192,1024] @ B(bf16,[1024,256] given as BT[256][1024]) + bias.
// Block = 16 rows x full 256 cols; 4 waves, wave w -> cols [64w, 64w+64) as 4
// 16x16 frags. K-permutation-invariant fragment loads (same (gq,e)->k map for
// A and B), so only the C/D layout (col=lane&15, row=4*(lane>>4)+e) matters.
__global__ __launch_bounds__(256) void gemm_kernel(const unsigned short* __restrict__ A,
                                                   const unsigned short* __restrict__ BT,
                                                   const float* __restrict__ bias,
                                                   float* __restrict__ out) {
    const int wave = threadIdx.x >> 6;
    const int lane = threadIdx.x & 63;
    const int r  = lane & 15;   // A row / B col within frag
    const int gq = lane >> 4;   // k group
    const size_t row0 = (size_t)blockIdx.x * 16;
    const int col0 = wave * 64;

    f32x4 acc[4] = {{0.f,0.f,0.f,0.f},{0.f,0.f,0.f,0.f},{0.f,0.f,0.f,0.f},{0.f,0.f,0.f,0.f}};

    const size_t arow = (row0 + r) * KD + gq * 8;
    size_t brow[4];
#pragma unroll
    for (int fc = 0; fc < 4; ++fc)
        brow[fc] = (size_t)(col0 + fc * 16 + r) * KD + gq * 8;

    for (int k0 = 0; k0 < KD; k0 += 32) {
        bf16x8 af = *(const bf16x8*)(A + arow + k0);
#pragma unroll
        for (int fc = 0; fc < 4; ++fc) {
            bf16x8 bfr = *(const bf16x8*)(BT + brow[fc] + k0);
            acc[fc] = __builtin_amdgcn_mfma_f32_16x16x32_bf16(af, bfr, acc[fc], 0, 0, 0);
        }
    }

#pragma unroll
    for (int fc = 0; fc < 4; ++fc) {
        int col = col0 + fc * 16 + r;
        float bv = bias[col];
#pragma unroll
        for (int e = 0; e < 4; ++e) {
            size_t row = row0 + gq * 4 + e;
            out[row * NOUT + col] = acc[fc][e] + bv;
        }
    }
}

extern "C" void kernel_launch(void* const* d_in, const int* in_sizes, int n_in,
                              void* d_out, int out_size, void* d_ws, size_t ws_size,
                              hipStream_t stream) {
    const float* h     = (const float*)d_in[0];
    const int*   batch = (const int*)d_in[1];
    const float* W     = (const float*)d_in[2];
    const float* b     = (const float*)d_in[3];
    float* out = (float*)d_out;

    const int N = in_sizes[0] / DIM;  // 500000 (unambiguous regardless of batch dtype)

    // workspace layout
    char* ws = (char*)d_ws;
    int* offs = (int*)ws;                                        // (NG+1) ints
    unsigned short* WT = (unsigned short*)(ws + 65536);          // 256*1024 bf16 = 512 KB
    unsigned short* hc = (unsigned short*)(ws + 65536 + 524288); // 8192*1024 bf16 = 16 MB

    find_offsets_kernel<<<(NG + 256) / 256, 256, 0, stream>>>(batch, N, offs);
    wt_kernel<<<(NOUT * KD) / 256, 256, 0, stream>>>(W, WT);
    stats_kernel<<<NG / 4, 256, 0, stream>>>(h, offs, hc);
    gemm_kernel<<<NG / 16, 256, 0, stream>>>(hc, WT, b, out);
}

// Round 3
// 141.844 us; speedup vs baseline: 1.1357x; 1.1357x over previous
//
#include <hip/hip_runtime.h>
#include <hip/hip_bf16.h>

// NodeToGlobal: per-graph segment {mean,min,max,std} over sorted batch ids,
// concat -> [G, 4D] -> @ W [4D, Gdim] + b.
// N=500000, D=256, G=8192, 4D=1024, Gdim=256.

#define DIM 256
#define NG 8192
#define KD 1024   // 4*DIM
#define NOUT 256  // g_dim

typedef __attribute__((ext_vector_type(8))) short bf16x8;
typedef __attribute__((ext_vector_type(4))) float f32x4;

__device__ __forceinline__ unsigned short f2bf(float x) {
    // round-to-nearest-even fp32 -> bf16 (finite inputs only)
    unsigned int u = __float_as_uint(x);
    u += 0x7fffu + ((u >> 16) & 1u);
    return (unsigned short)(u >> 16);
}

// WT[n][k] = bf16(W[k][n]) via LDS 64x64 tile transpose (coalesced both sides).
// W: [1024,256] f32 row-major; WT: [256][1024] bf16.
__global__ __launch_bounds__(256) void wt_kernel(const float* __restrict__ W,
                                                 unsigned short* __restrict__ WT) {
    __shared__ float tile[64][68];  // row stride 68*4=272B: 16B-aligned rows, broken pow2
    const int t = threadIdx.x;
    const int tk0 = (blockIdx.x & 15) * 64;  // 1024/64 = 16 k-tiles
    const int tn0 = (blockIdx.x >> 4) * 64;  // 256/64  =  4 n-tiles
    const int lk = t >> 2;              // 0..63
    const int ln = (t & 3) * 16;        // 0,16,32,48
#pragma unroll
    for (int j = 0; j < 16; j += 4) {
        float4 v = *(const float4*)&W[(size_t)(tk0 + lk) * NOUT + tn0 + ln + j];
        *(float4*)&tile[lk][ln + j] = v;
    }
    __syncthreads();
    const int on = t >> 2;              // output row (n) 0..63
    const int ok = (t & 3) * 16;        // k chunk
    unsigned short tmp[16];
#pragma unroll
    for (int j = 0; j < 16; ++j) tmp[j] = f2bf(tile[ok + j][on]);
    ushort4* dst = (ushort4*)&WT[(size_t)(tn0 + on) * KD + tk0 + ok];
#pragma unroll
    for (int j = 0; j < 4; ++j)
        dst[j] = make_ushort4(tmp[4 * j], tmp[4 * j + 1], tmp[4 * j + 2], tmp[4 * j + 3]);
}

// One wave per graph; lanes 0/1 binary-search the segment bounds (batch is
// sorted), then the wave streams rows with 4-row unrolled nontemporal f32x4
// loads (4KB burst in flight per wave). Lane owns dims [4*lane, 4*lane+4).
__global__ __launch_bounds__(256) void stats_kernel(const float* __restrict__ h,
                                                    const int* __restrict__ batch,
                                                    int N,
                                                    unsigned short* __restrict__ hc) {
    const int wave = threadIdx.x >> 6;
    const int lane = threadIdx.x & 63;
    const int g = (blockIdx.x << 2) + wave;

    // int64 detection: word[N-1] is the hi-word of element 249999 when batch is
    // int64 (== 0 since ids < 8192); for int32 it's the max id (~8191).
    const bool is64 = (batch[N - 1] == 0);
    // lanes 0/1 search lower_bound(g) / lower_bound(g+1) in parallel
    int target = g + (lane & 1);
    int lo = 0, hi = N;
    while (lo < hi) {
        int mid = (lo + hi) >> 1;
        int v = is64 ? batch[2 * mid] : batch[mid];
        if (v < target) lo = mid + 1; else hi = mid;
    }
    const int start = __shfl(lo, 0);
    const int end = __shfl(lo, 1);

    float s0[4] = {0.f, 0.f, 0.f, 0.f}, s1[4] = {0.f, 0.f, 0.f, 0.f};
    float q0[4] = {0.f, 0.f, 0.f, 0.f}, q1[4] = {0.f, 0.f, 0.f, 0.f};
    float mn[4] = {INFINITY, INFINITY, INFINITY, INFINITY};
    float mx[4] = {-INFINITY, -INFINITY, -INFINITY, -INFINITY};

    const f32x4* __restrict__ hv = (const f32x4*)h;  // 64 f32x4 per row
    int r = start;
    for (; r + 4 <= end; r += 4) {
        f32x4 A = __builtin_nontemporal_load(hv + (size_t)r * 64 + lane);
        f32x4 B = __builtin_nontemporal_load(hv + (size_t)(r + 1) * 64 + lane);
        f32x4 C = __builtin_nontemporal_load(hv + (size_t)(r + 2) * 64 + lane);
        f32x4 D = __builtin_nontemporal_load(hv + (size_t)(r + 3) * 64 + lane);
#pragma unroll
        for (int i = 0; i < 4; ++i) {
            s0[i] += A[i]; q0[i] = fmaf(A[i], A[i], q0[i]);
            mn[i] = fminf(mn[i], A[i]); mx[i] = fmaxf(mx[i], A[i]);
            s1[i] += B[i]; q1[i] = fmaf(B[i], B[i], q1[i]);
            mn[i] = fminf(mn[i], B[i]); mx[i] = fmaxf(mx[i], B[i]);
            s0[i] += C[i]; q0[i] = fmaf(C[i], C[i], q0[i]);
            mn[i] = fminf(mn[i], C[i]); mx[i] = fmaxf(mx[i], C[i]);
            s1[i] += D[i]; q1[i] = fmaf(D[i], D[i], q1[i]);
            mn[i] = fminf(mn[i], D[i]); mx[i] = fmaxf(mx[i], D[i]);
        }
    }
    for (; r < end; ++r) {
        f32x4 A = __builtin_nontemporal_load(hv + (size_t)r * 64 + lane);
#pragma unroll
        for (int i = 0; i < 4; ++i) {
            s0[i] += A[i]; q0[i] = fmaf(A[i], A[i], q0[i]);
            mn[i] = fminf(mn[i], A[i]); mx[i] = fmaxf(mx[i], A[i]);
        }
    }

    const int cnt = end - start;
    const float cf = (float)cnt;
    const float inv = cnt > 0 ? 1.f / cf : 0.f;
    const float invm1 = 1.f / fmaxf(cf - 1.f, 1.f);
    float mean[4], sd[4];
#pragma unroll
    for (int i = 0; i < 4; ++i) {
        float s = s0[i] + s1[i];
        float q = q0[i] + q1[i];
        mean[i] = s * inv;                               // 0 when empty
        float var = (q - mean[i] * s) * invm1;           // unbiased
        sd[i] = sqrtf(fmaxf(var, 0.f));
        if (cnt == 0) { mn[i] = 0.f; mx[i] = 0.f; }
    }

    ushort4* ob = (ushort4*)hc + (size_t)g * 256;  // 1024 bf16 = 256 ushort4 per row
    ob[lane]       = make_ushort4(f2bf(mean[0]), f2bf(mean[1]), f2bf(mean[2]), f2bf(mean[3]));
    ob[64 + lane]  = make_ushort4(f2bf(mn[0]),   f2bf(mn[1]),   f2bf(mn[2]),   f2bf(mn[3]));
    ob[128 + lane] = make_ushort4(f2bf(mx[0]),   f2bf(mx[1]),   f2bf(mx[2]),   f2bf(mx[3]));
    ob[192 + lane] = make_ushort4(f2bf(sd[0]),   f2bf(sd[1]),   f2bf(sd[2]),   f2bf(sd[3]));
}

// C[8192,256] = A(bf16)[8192,1024] @ B(bf16 as BT[256][1024]) + bias.
// Block = 16 rows x 256 cols; wave w -> cols [64w, 64w+64) as 4 16x16 frags.
// K-permutation-invariant fragment loads (same (gq,e)->k map for A and B);
// C/D layout: col=lane&15, row=4*(lane>>4)+e (HW-verified).
__global__ __launch_bounds__(256) void gemm_kernel(const unsigned short* __restrict__ A,
                                                   const unsigned short* __restrict__ BT,
                                                   const float* __restrict__ bias,
                                                   float* __restrict__ out) {
    const int wave = threadIdx.x >> 6;
    const int lane = threadIdx.x & 63;
    const int r  = lane & 15;   // A row / B col within frag
    const int gq = lane >> 4;   // k group
    const size_t row0 = (size_t)blockIdx.x * 16;
    const int col0 = wave * 64;

    f32x4 acc[4] = {{0.f,0.f,0.f,0.f},{0.f,0.f,0.f,0.f},{0.f,0.f,0.f,0.f},{0.f,0.f,0.f,0.f}};

    const size_t arow = (row0 + r) * KD + gq * 8;
    size_t brow[4];
#pragma unroll
    for (int fc = 0; fc < 4; ++fc)
        brow[fc] = (size_t)(col0 + fc * 16 + r) * KD + gq * 8;

#pragma unroll 2
    for (int k0 = 0; k0 < KD; k0 += 32) {
        bf16x8 af = *(const bf16x8*)(A + arow + k0);
#pragma unroll
        for (int fc = 0; fc < 4; ++fc) {
            bf16x8 bfr = *(const bf16x8*)(BT + brow[fc] + k0);
            acc[fc] = __builtin_amdgcn_mfma_f32_16x16x32_bf16(af, bfr, acc[fc], 0, 0, 0);
        }
    }

#pragma unroll
    for (int fc = 0; fc < 4; ++fc) {
        int col = col0 + fc * 16 + r;
        float bv = bias[col];
#pragma unroll
        for (int e = 0; e < 4; ++e) {
            size_t row = row0 + gq * 4 + e;
            out[row * NOUT + col] = acc[fc][e] + bv;
        }
    }
}

extern "C" void kernel_launch(void* const* d_in, const int* in_sizes, int n_in,
                              void* d_out, int out_size, void* d_ws, size_t ws_size,
                              hipStream_t stream) {
    const float* h     = (const float*)d_in[0];
    const int*   batch = (const int*)d_in[1];
    const float* W     = (const float*)d_in[2];
    const float* b     = (const float*)d_in[3];
    float* out = (float*)d_out;

    const int N = in_sizes[0] / DIM;  // 500000 (unambiguous regardless of batch dtype)

    // workspace layout
    char* ws = (char*)d_ws;
    unsigned short* WT = (unsigned short*)ws;             // 256*1024 bf16 = 512 KB
    unsigned short* hc = (unsigned short*)(ws + 524288);  // 8192*1024 bf16 = 16 MB

    wt_kernel<<<64, 256, 0, stream>>>(W, WT);
    stats_kernel<<<NG / 4, 256, 0, stream>>>(h, batch, N, hc);
    gemm_kernel<<<NG / 16, 256, 0, stream>>>(hc, WT, b, out);
}

// Round 4
// 118.675 us; speedup vs baseline: 1.3575x; 1.1952x over previous
//
#include <hip/hip_runtime.h>
#include <hip/hip_bf16.h>

// NodeToGlobal: per-graph segment {mean,min,max,std} over sorted batch ids,
// concat -> [G, 4D] -> @ W [4D, Gdim] + b.
// N=500000, D=256, G=8192, 4D=1024, Gdim=256.
//
// GEMM operands are stored in an MFMA-native "octet" layout so fragment loads
// are fully coalesced (1 KB contiguous per wave-load):
//   A'[tile][o][r][e] = hc[tile*16 + r][o*8 + e]   (tile = g/16, o = k/8)
//   B'[ct][o][c][e]   = W[o*8 + e][ct*16 + c]      (ct = n/16)

#define DIM 256
#define NG 8192
#define KD 1024   // 4*DIM
#define NOUT 256  // g_dim

typedef __attribute__((ext_vector_type(8))) short bf16x8;
typedef __attribute__((ext_vector_type(4))) float f32x4;

__device__ __forceinline__ unsigned short f2bf(float x) {
    // round-to-nearest-even fp32 -> bf16 (finite inputs only)
    unsigned int u = __float_as_uint(x);
    u += 0x7fffu + ((u >> 16) & 1u);
    return (unsigned short)(u >> 16);
}

// Fused prep: blocks [0,64) transpose W -> B' (bf16); blocks [64,64+2048)
// compute per-graph stats -> A' (bf16). Independent work, one dispatch.
__global__ __launch_bounds__(256) void prep_kernel(const float* __restrict__ W,
                                                   const float* __restrict__ h,
                                                   const int* __restrict__ batch,
                                                   int N,
                                                   unsigned short* __restrict__ WT,
                                                   unsigned short* __restrict__ hc) {
    __shared__ float tile[64][68];  // wt-part LDS transpose tile

    if (blockIdx.x < 64) {
        // ---- W transpose + bf16 cast into B' octet layout ----
        const int t = threadIdx.x;
        const int tk0 = ((int)blockIdx.x & 15) * 64;  // 16 k-tiles
        const int tn0 = ((int)blockIdx.x >> 4) * 64;  // 4 n-tiles
        const int lk = t >> 2;
        const int ln = (t & 3) * 16;
#pragma unroll
        for (int j = 0; j < 16; j += 4) {
            float4 v = *(const float4*)&W[(size_t)(tk0 + lk) * NOUT + tn0 + ln + j];
            *(float4*)&tile[lk][ln + j] = v;
        }
        __syncthreads();
        const int on = t >> 2;           // n within tile
        const int ok = (t & 3) * 16;     // k chunk of 16
        unsigned short tmp[16];
#pragma unroll
        for (int j = 0; j < 16; ++j) tmp[j] = f2bf(tile[ok + j][on]);
        const int n = tn0 + on;
        const int ct = n >> 4;
        const int c = n & 15;
        const int o0 = (tk0 + ok) >> 3;  // first octet of this 16-k chunk
        bf16x8 lo, hi;
#pragma unroll
        for (int j = 0; j < 8; ++j) { lo[j] = (short)tmp[j]; hi[j] = (short)tmp[8 + j]; }
        *(bf16x8*)&WT[(size_t)(((ct * 128 + o0) * 16 + c)) * 8]     = lo;
        *(bf16x8*)&WT[(size_t)(((ct * 128 + o0 + 1) * 16 + c)) * 8] = hi;
        return;
    }

    // ---- per-graph stats ----
    const int wave = threadIdx.x >> 6;
    const int lane = threadIdx.x & 63;
    const int g = (((int)blockIdx.x - 64) << 2) + wave;

    // int64 detection: word[N-1] is the hi-word of element (N-1)/2 when batch
    // is int64 (== 0 since ids < 8192); for int32 it's the max id (~8191).
    const bool is64 = (batch[N - 1] == 0);
    // lanes 0/1 search lower_bound(g) / lower_bound(g+1) in parallel
    int target = g + (lane & 1);
    int lo = 0, hi = N;
    while (lo < hi) {
        int mid = (lo + hi) >> 1;
        int v = is64 ? batch[2 * mid] : batch[mid];
        if (v < target) lo = mid + 1; else hi = mid;
    }
    const int start = __shfl(lo, 0);
    const int end = __shfl(lo, 1);

    float s0[4] = {0.f, 0.f, 0.f, 0.f}, s1[4] = {0.f, 0.f, 0.f, 0.f};
    float q0[4] = {0.f, 0.f, 0.f, 0.f}, q1[4] = {0.f, 0.f, 0.f, 0.f};
    float mn[4] = {INFINITY, INFINITY, INFINITY, INFINITY};
    float mx[4] = {-INFINITY, -INFINITY, -INFINITY, -INFINITY};

    const f32x4* __restrict__ hv = (const f32x4*)h;  // 64 f32x4 per row
    int r = start;
    for (; r + 4 <= end; r += 4) {
        f32x4 A = __builtin_nontemporal_load(hv + (size_t)r * 64 + lane);
        f32x4 B = __builtin_nontemporal_load(hv + (size_t)(r + 1) * 64 + lane);
        f32x4 C = __builtin_nontemporal_load(hv + (size_t)(r + 2) * 64 + lane);
        f32x4 D = __builtin_nontemporal_load(hv + (size_t)(r + 3) * 64 + lane);
#pragma unroll
        for (int i = 0; i < 4; ++i) {
            s0[i] += A[i]; q0[i] = fmaf(A[i], A[i], q0[i]);
            mn[i] = fminf(mn[i], A[i]); mx[i] = fmaxf(mx[i], A[i]);
            s1[i] += B[i]; q1[i] = fmaf(B[i], B[i], q1[i]);
            mn[i] = fminf(mn[i], B[i]); mx[i] = fmaxf(mx[i], B[i]);
            s0[i] += C[i]; q0[i] = fmaf(C[i], C[i], q0[i]);
            mn[i] = fminf(mn[i], C[i]); mx[i] = fmaxf(mx[i], C[i]);
            s1[i] += D[i]; q1[i] = fmaf(D[i], D[i], q1[i]);
            mn[i] = fminf(mn[i], D[i]); mx[i] = fmaxf(mx[i], D[i]);
        }
    }
    for (; r < end; ++r) {
        f32x4 A = __builtin_nontemporal_load(hv + (size_t)r * 64 + lane);
#pragma unroll
        for (int i = 0; i < 4; ++i) {
            s0[i] += A[i]; q0[i] = fmaf(A[i], A[i], q0[i]);
            mn[i] = fminf(mn[i], A[i]); mx[i] = fmaxf(mx[i], A[i]);
        }
    }

    const int cnt = end - start;
    const float cf = (float)cnt;
    const float inv = cnt > 0 ? 1.f / cf : 0.f;
    const float invm1 = 1.f / fmaxf(cf - 1.f, 1.f);
    float mean[4], sd[4];
#pragma unroll
    for (int i = 0; i < 4; ++i) {
        float s = s0[i] + s1[i];
        float q = q0[i] + q1[i];
        mean[i] = s * inv;                               // 0 when empty
        float var = (q - mean[i] * s) * invm1;           // unbiased
        sd[i] = sqrtf(fmaxf(var, 0.f));
        if (cnt == 0) { mn[i] = 0.f; mx[i] = 0.f; }
    }

    // A' octet-layout writes: stat st, dims 4*lane..4*lane+3 ->
    // octet o = st*32 + lane/2, elem base 4*(lane&1).
    const int gt = g >> 4;
    const int gr = g & 15;
    ushort4* hc4 = (ushort4*)hc;
    const size_t base = ((size_t)gt * 128) ;
    const int oo = (lane >> 1);
    const int half = lane & 1;
#define STORE_STAT(st, v)                                                         \
    hc4[(((base + (st) * 32 + oo) * 16 + gr) << 1) + half] =                      \
        make_ushort4(f2bf(v[0]), f2bf(v[1]), f2bf(v[2]), f2bf(v[3]))
    STORE_STAT(0, mean);
    STORE_STAT(1, mn);
    STORE_STAT(2, mx);
    STORE_STAT(3, sd);
#undef STORE_STAT
}

// C[8192,256] = A'(bf16 octet layout) @ B'(bf16 octet layout) + bias.
// Block = 16 rows x 256 cols; wave w -> cols [64w,64w+64) as 4 16x16 frags.
// Per k-step every fragment load is 1 KB contiguous per wave (coalesced).
// K-permutation-invariant fragment loads (same (gq,e)->k map for A and B);
// C/D layout: col=lane&15, row=4*(lane>>4)+e (HW-verified).
__global__ __launch_bounds__(256) void gemm_kernel(const unsigned short* __restrict__ A,
                                                   const unsigned short* __restrict__ BT,
                                                   const float* __restrict__ bias,
                                                   float* __restrict__ out) {
    const int wave = threadIdx.x >> 6;
    const int lane = threadIdx.x & 63;
    const int r  = lane & 15;   // A row / B col within frag
    const int gq = lane >> 4;   // k octet within 32-k step

    f32x4 acc[4] = {{0.f,0.f,0.f,0.f},{0.f,0.f,0.f,0.f},{0.f,0.f,0.f,0.f},{0.f,0.f,0.f,0.f}};

    const unsigned short* Ab = A + ((((size_t)blockIdx.x * 128 + gq) * 16 + r) << 3);
    const unsigned short* Bb[4];
#pragma unroll
    for (int fc = 0; fc < 4; ++fc)
        Bb[fc] = BT + ((((size_t)(wave * 4 + fc) * 128 + gq) * 16 + r) << 3);

#pragma unroll 2
    for (int t = 0; t < 32; ++t) {
        bf16x8 af = *(const bf16x8*)(Ab + t * 512);  // 4 octets * 128 elems
#pragma unroll
        for (int fc = 0; fc < 4; ++fc) {
            bf16x8 bfr = *(const bf16x8*)(Bb[fc] + t * 512);
            acc[fc] = __builtin_amdgcn_mfma_f32_16x16x32_bf16(af, bfr, acc[fc], 0, 0, 0);
        }
    }

    const size_t row0 = (size_t)blockIdx.x * 16;
#pragma unroll
    for (int fc = 0; fc < 4; ++fc) {
        int col = wave * 64 + fc * 16 + r;
        float bv = bias[col];
#pragma unroll
        for (int e = 0; e < 4; ++e) {
            size_t row = row0 + gq * 4 + e;
            out[row * NOUT + col] = acc[fc][e] + bv;
        }
    }
}

extern "C" void kernel_launch(void* const* d_in, const int* in_sizes, int n_in,
                              void* d_out, int out_size, void* d_ws, size_t ws_size,
                              hipStream_t stream) {
    const float* h     = (const float*)d_in[0];
    const int*   batch = (const int*)d_in[1];
    const float* W     = (const float*)d_in[2];
    const float* b     = (const float*)d_in[3];
    float* out = (float*)d_out;

    const int N = in_sizes[0] / DIM;  // 500000 (unambiguous regardless of batch dtype)

    // workspace layout
    char* ws = (char*)d_ws;
    unsigned short* WT = (unsigned short*)ws;             // B': 256*1024 bf16 = 512 KB
    unsigned short* hc = (unsigned short*)(ws + 524288);  // A': 8192*1024 bf16 = 16 MB

    prep_kernel<<<64 + NG / 4, 256, 0, stream>>>(W, h, batch, N, WT, hc);
    gemm_kernel<<<NG / 16, 256, 0, stream>>>(hc, WT, b, out);
}

// Round 5
// 100.771 us; speedup vs baseline: 1.5986x; 1.1777x over previous
//
#include <hip/hip_runtime.h>
#include <hip/hip_bf16.h>

// NodeToGlobal: per-graph segment {mean,min,max,std} over sorted batch ids,
// concat -> [G, 4D] -> @ W [4D, Gdim] + b.
// N=500000, D=256, G=8192, 4D=1024, Gdim=256.
//
// Fused design: prep kernel builds B' (W transposed to MFMA-octet bf16) and
// the segment offset table; the main kernel computes per-graph stats for a
// 32-graph tile into LDS (XOR-swizzled) and immediately runs the 32x256 GEMM
// tile from LDS-A + L2-resident B'. No hc round-trip through HBM.
//
// Octet layout (coalesced MFMA fragments): X'[tile16][o][r][e] holds
// X[tile16*16 + r][o*8 + e].

#define DIM 256
#define NG 8192
#define KD 1024   // 4*DIM
#define NOUT 256  // g_dim

typedef __attribute__((ext_vector_type(8))) short bf16x8;
typedef __attribute__((ext_vector_type(4))) float f32x4;

__device__ __forceinline__ unsigned short f2bf(float x) {
    // round-to-nearest-even fp32 -> bf16 (finite inputs only)
    unsigned int u = __float_as_uint(x);
    u += 0x7fffu + ((u >> 16) & 1u);
    return (unsigned short)(u >> 16);
}

__device__ __forceinline__ unsigned int pack2(float a, float b) {
    return (unsigned int)f2bf(a) | ((unsigned int)f2bf(b) << 16);
}

// prep: blocks [0,64): W -> B' octet bf16 (LDS 64x64 transpose tiles);
//       blocks [64,97): offs[t] = lower_bound(batch, t), t in [0, 8192].
__global__ __launch_bounds__(256) void prep_kernel(const float* __restrict__ W,
                                                   const int* __restrict__ batch,
                                                   int N,
                                                   unsigned short* __restrict__ WT,
                                                   int* __restrict__ offs) {
    __shared__ float tile[64][68];

    if (blockIdx.x >= 64) {
        int t = ((int)blockIdx.x - 64) * 256 + (int)threadIdx.x;
        if (t > NG) return;
        // int64 detection: word[N-1] is the hi-word of element (N-1)/2 when
        // batch is int64 (== 0 since ids < 8192); for int32 it's the max id.
        const bool is64 = (batch[N - 1] == 0);
        int lo = 0, hi = N;
        while (lo < hi) {
            int mid = (lo + hi) >> 1;
            int v = is64 ? batch[2 * mid] : batch[mid];
            if (v < t) lo = mid + 1; else hi = mid;
        }
        offs[t] = lo;
        return;
    }

    // ---- W transpose + bf16 cast into B' octet layout ----
    const int t = threadIdx.x;
    const int tk0 = ((int)blockIdx.x & 15) * 64;  // 16 k-tiles
    const int tn0 = ((int)blockIdx.x >> 4) * 64;  // 4 n-tiles
    const int lk = t >> 2;
    const int ln = (t & 3) * 16;
#pragma unroll
    for (int j = 0; j < 16; j += 4) {
        float4 v = *(const float4*)&W[(size_t)(tk0 + lk) * NOUT + tn0 + ln + j];
        *(float4*)&tile[lk][ln + j] = v;
    }
    __syncthreads();
    const int on = t >> 2;           // n within tile
    const int ok = (t & 3) * 16;     // k chunk of 16
    unsigned short tmp[16];
#pragma unroll
    for (int j = 0; j < 16; ++j) tmp[j] = f2bf(tile[ok + j][on]);
    const int n = tn0 + on;
    const int ct = n >> 4;
    const int c = n & 15;
    const int o0 = (tk0 + ok) >> 3;
    bf16x8 lo8, hi8;
#pragma unroll
    for (int j = 0; j < 8; ++j) { lo8[j] = (short)tmp[j]; hi8[j] = (short)tmp[8 + j]; }
    *(bf16x8*)&WT[(size_t)(((ct * 128 + o0) * 16 + c)) * 8]     = lo8;
    *(bf16x8*)&WT[(size_t)(((ct * 128 + o0 + 1) * 16 + c)) * 8] = hi8;
}

// Fused stats+GEMM. 256 blocks x 512 threads (8 waves). Block owns graphs
// [32b, 32b+32). Wave w computes stats for graphs 32b+4w..+3 (8-row NT f32x4
// bursts), writes bf16 rows to LDS A-tile [32][1024] with byte^=((row&7)<<4)
// swizzle (conflict-free ds_write_b64 AND ds_read_b128). After barrier, wave
// (wr=w>>2, wc=w&3) computes out rows [16wr..+16) x cols [64wc..+64).
__global__ __launch_bounds__(512) void fused_kernel(const float* __restrict__ h,
                                                    const int* __restrict__ offs,
                                                    const unsigned short* __restrict__ BT,
                                                    const float* __restrict__ bias,
                                                    float* __restrict__ out) {
    __shared__ unsigned short As[32 * 1024];  // 64 KB
    const int w = threadIdx.x >> 6;
    const int lane = threadIdx.x & 63;
    const int tile = blockIdx.x;
    const int g0 = tile * 32 + w * 4;

    // lanes 0..4 hold offs[g0+lane]
    const int ob = offs[g0 + (lane < 5 ? lane : 4)];
    const f32x4* __restrict__ hv = (const f32x4*)h;  // 64 f32x4 per row

    for (int i = 0; i < 4; ++i) {
        const int start = __shfl(ob, i);
        const int end = __shfl(ob, i + 1);

        float s0[4] = {0.f,0.f,0.f,0.f}, s1[4] = {0.f,0.f,0.f,0.f};
        float q0[4] = {0.f,0.f,0.f,0.f}, q1[4] = {0.f,0.f,0.f,0.f};
        float mn[4] = {INFINITY, INFINITY, INFINITY, INFINITY};
        float mx[4] = {-INFINITY, -INFINITY, -INFINITY, -INFINITY};

        int r = start;
        for (; r + 8 <= end; r += 8) {
            f32x4 v[8];
#pragma unroll
            for (int j = 0; j < 8; ++j)
                v[j] = __builtin_nontemporal_load(hv + (size_t)(r + j) * 64 + lane);
#pragma unroll
            for (int j = 0; j < 8; ++j) {
                if (j & 1) {
#pragma unroll
                    for (int i2 = 0; i2 < 4; ++i2) {
                        s1[i2] += v[j][i2]; q1[i2] = fmaf(v[j][i2], v[j][i2], q1[i2]);
                        mn[i2] = fminf(mn[i2], v[j][i2]); mx[i2] = fmaxf(mx[i2], v[j][i2]);
                    }
                } else {
#pragma unroll
                    for (int i2 = 0; i2 < 4; ++i2) {
                        s0[i2] += v[j][i2]; q0[i2] = fmaf(v[j][i2], v[j][i2], q0[i2]);
                        mn[i2] = fminf(mn[i2], v[j][i2]); mx[i2] = fmaxf(mx[i2], v[j][i2]);
                    }
                }
            }
        }
        for (; r < end; ++r) {
            f32x4 a = __builtin_nontemporal_load(hv + (size_t)r * 64 + lane);
#pragma unroll
            for (int i2 = 0; i2 < 4; ++i2) {
                s0[i2] += a[i2]; q0[i2] = fmaf(a[i2], a[i2], q0[i2]);
                mn[i2] = fminf(mn[i2], a[i2]); mx[i2] = fmaxf(mx[i2], a[i2]);
            }
        }

        const int cnt = end - start;
        const float cf = (float)cnt;
        const float inv = cnt > 0 ? 1.f / cf : 0.f;
        const float invm1 = 1.f / fmaxf(cf - 1.f, 1.f);
        float mean[4], sd[4];
#pragma unroll
        for (int i2 = 0; i2 < 4; ++i2) {
            float s = s0[i2] + s1[i2];
            float q = q0[i2] + q1[i2];
            mean[i2] = s * inv;                          // 0 when empty
            float var = (q - mean[i2] * s) * invm1;      // unbiased
            sd[i2] = sqrtf(fmaxf(var, 0.f));
            if (cnt == 0) { mn[i2] = 0.f; mx[i2] = 0.f; }
        }

        // LDS write: row lr, stat st at elems st*256 + 4*lane (8 bytes).
        const int lr = w * 4 + i;
        const unsigned int rx = (unsigned int)((lr & 7) << 4);
        char* base = (char*)As;
        const unsigned int b0 = (unsigned int)(lr * 2048 + lane * 8);
        *(uint2*)(base + ((b0 + 0)    ^ rx)) = make_uint2(pack2(mean[0], mean[1]), pack2(mean[2], mean[3]));
        *(uint2*)(base + ((b0 + 512)  ^ rx)) = make_uint2(pack2(mn[0], mn[1]),     pack2(mn[2], mn[3]));
        *(uint2*)(base + ((b0 + 1024) ^ rx)) = make_uint2(pack2(mx[0], mx[1]),     pack2(mx[2], mx[3]));
        *(uint2*)(base + ((b0 + 1536) ^ rx)) = make_uint2(pack2(sd[0], sd[1]),     pack2(sd[2], sd[3]));
    }

    __syncthreads();

    // ---- GEMM: rows [16wr..+16) x cols [64wc..+64) ----
    const int wr = w >> 2, wc = w & 3;
    const int fr = lane & 15;   // A row / B col within frag
    const int gq = lane >> 4;   // k octet within 32-k step
    const int rowr = wr * 16 + fr;
    const unsigned int arx = (unsigned int)((fr & 7) << 4);
    const unsigned int abase = (unsigned int)(rowr * 2048 + gq * 16);

    f32x4 acc[4] = {{0.f,0.f,0.f,0.f},{0.f,0.f,0.f,0.f},{0.f,0.f,0.f,0.f},{0.f,0.f,0.f,0.f}};

    const unsigned short* Bb[4];
#pragma unroll
    for (int fc = 0; fc < 4; ++fc)
        Bb[fc] = BT + ((((size_t)(wc * 4 + fc) * 128 + gq) * 16 + fr) << 3);

#pragma unroll 2
    for (int t = 0; t < 32; ++t) {
        bf16x8 af = *(const bf16x8*)((const char*)As + ((abase + t * 64) ^ arx));
#pragma unroll
        for (int fc = 0; fc < 4; ++fc) {
            bf16x8 bfr = *(const bf16x8*)(Bb[fc] + t * 512);
            acc[fc] = __builtin_amdgcn_mfma_f32_16x16x32_bf16(af, bfr, acc[fc], 0, 0, 0);
        }
    }

    const size_t row0 = (size_t)tile * 32;
#pragma unroll
    for (int fc = 0; fc < 4; ++fc) {
        int col = wc * 64 + fc * 16 + fr;
        float bv = bias[col];
#pragma unroll
        for (int e = 0; e < 4; ++e) {
            size_t row = row0 + wr * 16 + gq * 4 + e;
            out[row * NOUT + col] = acc[fc][e] + bv;
        }
    }
}

extern "C" void kernel_launch(void* const* d_in, const int* in_sizes, int n_in,
                              void* d_out, int out_size, void* d_ws, size_t ws_size,
                              hipStream_t stream) {
    const float* h     = (const float*)d_in[0];
    const int*   batch = (const int*)d_in[1];
    const float* W     = (const float*)d_in[2];
    const float* b     = (const float*)d_in[3];
    float* out = (float*)d_out;

    const int N = in_sizes[0] / DIM;  // 500000 (unambiguous regardless of batch dtype)

    // workspace layout
    char* ws = (char*)d_ws;
    unsigned short* WT = (unsigned short*)ws;      // B': 256*1024 bf16 = 512 KB
    int* offs = (int*)(ws + 524288);               // 8193 ints

    prep_kernel<<<97, 256, 0, stream>>>(W, batch, N, WT, offs);
    fused_kernel<<<256, 512, 0, stream>>>(h, offs, WT, b, out);
}

// Round 6
// 99.347 us; speedup vs baseline: 1.6216x; 1.0143x over previous
//
#include <hip/hip_runtime.h>
#include <hip/hip_bf16.h>

// NodeToGlobal: per-graph segment {mean,min,max,std} over sorted batch ids,
// concat -> [G, 4D] -> @ W [4D, Gdim] + b.
// N=500000, D=256, G=8192, 4D=1024, Gdim=256.
//
// Fused design: prep kernel builds B' (W transposed to MFMA-octet bf16) and
// the segment offset table; the main kernel computes per-graph stats for a
// 16-graph tile into LDS (XOR-swizzled) and immediately runs the 16x256 GEMM
// tile from LDS-A + L2-resident B'. 512 blocks -> 2 blocks/CU co-resident so
// barrier waits of one block are covered by the other block's streaming.
//
// Octet layout (coalesced MFMA fragments): X'[tile16][o][r][e] holds
// X[tile16*16 + r][o*8 + e].

#define DIM 256
#define NG 8192
#define KD 1024   // 4*DIM
#define NOUT 256  // g_dim

typedef __attribute__((ext_vector_type(8))) short bf16x8;
typedef __attribute__((ext_vector_type(4))) float f32x4;

__device__ __forceinline__ unsigned short f2bf(float x) {
    // round-to-nearest-even fp32 -> bf16 (finite inputs only)
    unsigned int u = __float_as_uint(x);
    u += 0x7fffu + ((u >> 16) & 1u);
    return (unsigned short)(u >> 16);
}

__device__ __forceinline__ unsigned int pack2(float a, float b) {
    return (unsigned int)f2bf(a) | ((unsigned int)f2bf(b) << 16);
}

// prep: blocks [0,64): W -> B' octet bf16 (LDS 64x64 transpose tiles);
//       blocks [64,97): offs[t] = lower_bound(batch, t), t in [0, 8192].
__global__ __launch_bounds__(256) void prep_kernel(const float* __restrict__ W,
                                                   const int* __restrict__ batch,
                                                   int N,
                                                   unsigned short* __restrict__ WT,
                                                   int* __restrict__ offs) {
    __shared__ float tile[64][68];

    if (blockIdx.x >= 64) {
        int t = ((int)blockIdx.x - 64) * 256 + (int)threadIdx.x;
        if (t > NG) return;
        // int64 detection: word[N-1] is the hi-word of element (N-1)/2 when
        // batch is int64 (== 0 since ids < 8192); for int32 it's the max id.
        const bool is64 = (batch[N - 1] == 0);
        int lo = 0, hi = N;
        while (lo < hi) {
            int mid = (lo + hi) >> 1;
            int v = is64 ? batch[2 * mid] : batch[mid];
            if (v < t) lo = mid + 1; else hi = mid;
        }
        offs[t] = lo;
        return;
    }

    // ---- W transpose + bf16 cast into B' octet layout ----
    const int t = threadIdx.x;
    const int tk0 = ((int)blockIdx.x & 15) * 64;  // 16 k-tiles
    const int tn0 = ((int)blockIdx.x >> 4) * 64;  // 4 n-tiles
    const int lk = t >> 2;
    const int ln = (t & 3) * 16;
#pragma unroll
    for (int j = 0; j < 16; j += 4) {
        float4 v = *(const float4*)&W[(size_t)(tk0 + lk) * NOUT + tn0 + ln + j];
        *(float4*)&tile[lk][ln + j] = v;
    }
    __syncthreads();
    const int on = t >> 2;           // n within tile
    const int ok = (t & 3) * 16;     // k chunk of 16
    unsigned short tmp[16];
#pragma unroll
    for (int j = 0; j < 16; ++j) tmp[j] = f2bf(tile[ok + j][on]);
    const int n = tn0 + on;
    const int ct = n >> 4;
    const int c = n & 15;
    const int o0 = (tk0 + ok) >> 3;
    bf16x8 lo8, hi8;
#pragma unroll
    for (int j = 0; j < 8; ++j) { lo8[j] = (short)tmp[j]; hi8[j] = (short)tmp[8 + j]; }
    *(bf16x8*)&WT[(size_t)(((ct * 128 + o0) * 16 + c)) * 8]     = lo8;
    *(bf16x8*)&WT[(size_t)(((ct * 128 + o0 + 1) * 16 + c)) * 8] = hi8;
}

// Fused stats+GEMM. 512 blocks x 256 threads (4 waves). Block owns graphs
// [16b, 16b+16). Wave w computes stats for graphs 16b+4w..+3 (8-row NT f32x4
// bursts), writes bf16 rows to LDS A-tile [16][1024] with byte^=((row&7)<<4)
// swizzle (conflict-free ds_write_b64 AND ds_read_b128). After barrier, wave
// w computes out rows [0..16) x cols [64w..+64). 32 KB LDS -> multiple
// blocks/CU co-resident to absorb barrier waits.
__global__ __launch_bounds__(256, 4) void fused_kernel(const float* __restrict__ h,
                                                       const int* __restrict__ offs,
                                                       const unsigned short* __restrict__ BT,
                                                       const float* __restrict__ bias,
                                                       float* __restrict__ out) {
    __shared__ unsigned short As[16 * 1024];  // 32 KB
    const int w = threadIdx.x >> 6;
    const int lane = threadIdx.x & 63;
    const int tile = blockIdx.x;
    const int g0 = tile * 16 + w * 4;

    // lanes 0..4 hold offs[g0+lane]
    const int ob = offs[g0 + (lane < 5 ? lane : 4)];
    const f32x4* __restrict__ hv = (const f32x4*)h;  // 64 f32x4 per row

    for (int i = 0; i < 4; ++i) {
        const int start = __shfl(ob, i);
        const int end = __shfl(ob, i + 1);

        float s0[4] = {0.f,0.f,0.f,0.f}, s1[4] = {0.f,0.f,0.f,0.f};
        float q0[4] = {0.f,0.f,0.f,0.f}, q1[4] = {0.f,0.f,0.f,0.f};
        float mn[4] = {INFINITY, INFINITY, INFINITY, INFINITY};
        float mx[4] = {-INFINITY, -INFINITY, -INFINITY, -INFINITY};

        int r = start;
        for (; r + 8 <= end; r += 8) {
            f32x4 v[8];
#pragma unroll
            for (int j = 0; j < 8; ++j)
                v[j] = __builtin_nontemporal_load(hv + (size_t)(r + j) * 64 + lane);
#pragma unroll
            for (int j = 0; j < 8; ++j) {
                if (j & 1) {
#pragma unroll
                    for (int i2 = 0; i2 < 4; ++i2) {
                        s1[i2] += v[j][i2]; q1[i2] = fmaf(v[j][i2], v[j][i2], q1[i2]);
                        mn[i2] = fminf(mn[i2], v[j][i2]); mx[i2] = fmaxf(mx[i2], v[j][i2]);
                    }
                } else {
#pragma unroll
                    for (int i2 = 0; i2 < 4; ++i2) {
                        s0[i2] += v[j][i2]; q0[i2] = fmaf(v[j][i2], v[j][i2], q0[i2]);
                        mn[i2] = fminf(mn[i2], v[j][i2]); mx[i2] = fmaxf(mx[i2], v[j][i2]);
                    }
                }
            }
        }
        for (; r < end; ++r) {
            f32x4 a = __builtin_nontemporal_load(hv + (size_t)r * 64 + lane);
#pragma unroll
            for (int i2 = 0; i2 < 4; ++i2) {
                s0[i2] += a[i2]; q0[i2] = fmaf(a[i2], a[i2], q0[i2]);
                mn[i2] = fminf(mn[i2], a[i2]); mx[i2] = fmaxf(mx[i2], a[i2]);
            }
        }

        const int cnt = end - start;
        const float cf = (float)cnt;
        const float inv = cnt > 0 ? 1.f / cf : 0.f;
        const float invm1 = 1.f / fmaxf(cf - 1.f, 1.f);
        float mean[4], sd[4];
#pragma unroll
        for (int i2 = 0; i2 < 4; ++i2) {
            float s = s0[i2] + s1[i2];
            float q = q0[i2] + q1[i2];
            mean[i2] = s * inv;                          // 0 when empty
            float var = (q - mean[i2] * s) * invm1;      // unbiased
            sd[i2] = sqrtf(fmaxf(var, 0.f));
            if (cnt == 0) { mn[i2] = 0.f; mx[i2] = 0.f; }
        }

        // LDS write: row lr, stat st at elems st*256 + 4*lane (8 bytes).
        const int lr = w * 4 + i;
        const unsigned int rx = (unsigned int)((lr & 7) << 4);
        char* base = (char*)As;
        const unsigned int b0 = (unsigned int)(lr * 2048 + lane * 8);
        *(uint2*)(base + ((b0 + 0)    ^ rx)) = make_uint2(pack2(mean[0], mean[1]), pack2(mean[2], mean[3]));
        *(uint2*)(base + ((b0 + 512)  ^ rx)) = make_uint2(pack2(mn[0], mn[1]),     pack2(mn[2], mn[3]));
        *(uint2*)(base + ((b0 + 1024) ^ rx)) = make_uint2(pack2(mx[0], mx[1]),     pack2(mx[2], mx[3]));
        *(uint2*)(base + ((b0 + 1536) ^ rx)) = make_uint2(pack2(sd[0], sd[1]),     pack2(sd[2], sd[3]));
    }

    __syncthreads();

    // ---- GEMM: rows [0,16) x cols [64w..+64) ----
    const int fr = lane & 15;   // A row / B col within frag
    const int gq = lane >> 4;   // k octet within 32-k step
    const unsigned int arx = (unsigned int)((fr & 7) << 4);
    const unsigned int abase = (unsigned int)(fr * 2048 + gq * 16);

    f32x4 acc[4] = {{0.f,0.f,0.f,0.f},{0.f,0.f,0.f,0.f},{0.f,0.f,0.f,0.f},{0.f,0.f,0.f,0.f}};

    const unsigned short* Bb[4];
#pragma unroll
    for (int fc = 0; fc < 4; ++fc)
        Bb[fc] = BT + ((((size_t)(w * 4 + fc) * 128 + gq) * 16 + fr) << 3);

#pragma unroll 2
    for (int t = 0; t < 32; ++t) {
        bf16x8 af = *(const bf16x8*)((const char*)As + ((abase + t * 64) ^ arx));
#pragma unroll
        for (int fc = 0; fc < 4; ++fc) {
            bf16x8 bfr = *(const bf16x8*)(Bb[fc] + t * 512);
            acc[fc] = __builtin_amdgcn_mfma_f32_16x16x32_bf16(af, bfr, acc[fc], 0, 0, 0);
        }
    }

    const size_t row0 = (size_t)tile * 16;
#pragma unroll
    for (int fc = 0; fc < 4; ++fc) {
        int col = w * 64 + fc * 16 + fr;
        float bv = bias[col];
#pragma unroll
        for (int e = 0; e < 4; ++e) {
            size_t row = row0 + gq * 4 + e;
            out[row * NOUT + col] = acc[fc][e] + bv;
        }
    }
}

extern "C" void kernel_launch(void* const* d_in, const int* in_sizes, int n_in,
                              void* d_out, int out_size, void* d_ws, size_t ws_size,
                              hipStream_t stream) {
    const float* h     = (const float*)d_in[0];
    const int*   batch = (const int*)d_in[1];
    const float* W     = (const float*)d_in[2];
    const float* b     = (const float*)d_in[3];
    float* out = (float*)d_out;

    const int N = in_sizes[0] / DIM;  // 500000 (unambiguous regardless of batch dtype)

    // workspace layout
    char* ws = (char*)d_ws;
    unsigned short* WT = (unsigned short*)ws;      // B': 256*1024 bf16 = 512 KB
    int* offs = (int*)(ws + 524288);               // 8193 ints

    prep_kernel<<<97, 256, 0, stream>>>(W, batch, N, WT, offs);
    fused_kernel<<<NG / 16, 256, 0, stream>>>(h, offs, WT, b, out);
}

// Round 7
// 97.947 us; speedup vs baseline: 1.6447x; 1.0143x over previous
//
#include <hip/hip_runtime.h>
#include <hip/hip_bf16.h>

// NodeToGlobal: per-graph segment {mean,min,max,std} over sorted batch ids,
// concat -> [G, 4D] -> @ W [4D, Gdim] + b.
// N=500000, D=256, G=8192, 4D=1024, Gdim=256.
//
// Fused design: prep kernel builds B' (W transposed to MFMA-octet bf16) and
// the segment offset table; the main kernel streams each wave's 4 contiguous
// graphs as ONE unbroken 8-row-burst stream (graph boundaries are wave-
// uniform -> flush accumulators in-stream, bursts may straddle boundaries),
// writes the bf16 A-tile to XOR-swizzled LDS, then runs the 16x256 GEMM tile
// from LDS-A + L2-resident B'.
//
// Octet layout (coalesced MFMA fragments): X'[tile16][o][r][e] holds
// X[tile16*16 + r][o*8 + e].

#define DIM 256
#define NG 8192
#define KD 1024   // 4*DIM
#define NOUT 256  // g_dim

typedef __attribute__((ext_vector_type(8))) short bf16x8;
typedef __attribute__((ext_vector_type(4))) float f32x4;

__device__ __forceinline__ unsigned short f2bf(float x) {
    // round-to-nearest-even fp32 -> bf16 (finite inputs only)
    unsigned int u = __float_as_uint(x);
    u += 0x7fffu + ((u >> 16) & 1u);
    return (unsigned short)(u >> 16);
}

__device__ __forceinline__ unsigned int pack2(float a, float b) {
    return (unsigned int)f2bf(a) | ((unsigned int)f2bf(b) << 16);
}

// prep: blocks [0,64): W -> B' octet bf16 (LDS 64x64 transpose tiles);
//       blocks [64,97): offs[t] = lower_bound(batch, t), t in [0, 8192].
__global__ __launch_bounds__(256) void prep_kernel(const float* __restrict__ W,
                                                   const int* __restrict__ batch,
                                                   int N,
                                                   unsigned short* __restrict__ WT,
                                                   int* __restrict__ offs) {
    __shared__ float tile[64][68];

    if (blockIdx.x >= 64) {
        int t = ((int)blockIdx.x - 64) * 256 + (int)threadIdx.x;
        if (t > NG) return;
        // int64 detection: word[N-1] is the hi-word of element (N-1)/2 when
        // batch is int64 (== 0 since ids < 8192); for int32 it's the max id.
        const bool is64 = (batch[N - 1] == 0);
        int lo = 0, hi = N;
        while (lo < hi) {
            int mid = (lo + hi) >> 1;
            int v = is64 ? batch[2 * mid] : batch[mid];
            if (v < t) lo = mid + 1; else hi = mid;
        }
        offs[t] = lo;
        return;
    }

    // ---- W transpose + bf16 cast into B' octet layout ----
    const int t = threadIdx.x;
    const int tk0 = ((int)blockIdx.x & 15) * 64;  // 16 k-tiles
    const int tn0 = ((int)blockIdx.x >> 4) * 64;  // 4 n-tiles
    const int lk = t >> 2;
    const int ln = (t & 3) * 16;
#pragma unroll
    for (int j = 0; j < 16; j += 4) {
        float4 v = *(const float4*)&W[(size_t)(tk0 + lk) * NOUT + tn0 + ln + j];
        *(float4*)&tile[lk][ln + j] = v;
    }
    __syncthreads();
    const int on = t >> 2;           // n within tile
    const int ok = (t & 3) * 16;     // k chunk of 16
    unsigned short tmp[16];
#pragma unroll
    for (int j = 0; j < 16; ++j) tmp[j] = f2bf(tile[ok + j][on]);
    const int n = tn0 + on;
    const int ct = n >> 4;
    const int c = n & 15;
    const int o0 = (tk0 + ok) >> 3;
    bf16x8 lo8, hi8;
#pragma unroll
    for (int j = 0; j < 8; ++j) { lo8[j] = (short)tmp[j]; hi8[j] = (short)tmp[8 + j]; }
    *(bf16x8*)&WT[(size_t)(((ct * 128 + o0) * 16 + c)) * 8]     = lo8;
    *(bf16x8*)&WT[(size_t)(((ct * 128 + o0 + 1) * 16 + c)) * 8] = hi8;
}

// Fused stats+GEMM. 512 blocks x 256 threads (4 waves). Block owns graphs
// [16b, 16b+16); wave w owns graphs 16b+4w..+3 streamed as one contiguous
// row range with in-stream boundary flushes. LDS A-tile [16][1024] bf16,
// byte^=((row&7)<<4) swizzle (conflict-free ds_write_b64 + ds_read_b128).
// After barrier, wave w computes out rows [0..16) x cols [64w..+64).
__global__ __launch_bounds__(256) void fused_kernel(const float* __restrict__ h,
                                                    const int* __restrict__ offs,
                                                    const unsigned short* __restrict__ BT,
                                                    const float* __restrict__ bias,
                                                    float* __restrict__ out) {
    __shared__ unsigned short As[16 * 1024];  // 32 KB
    const int w = threadIdx.x >> 6;
    const int lane = threadIdx.x & 63;
    const int tile = blockIdx.x;
    const int g0 = tile * 16 + w * 4;

    // lanes 0..4 hold offs[g0+lane]; boundaries are wave-uniform via shfl.
    const int ob = offs[g0 + (lane < 5 ? lane : 4)];
    const int wave_start = __shfl(ob, 0);
    const int wave_end = __shfl(ob, 4);

    float s0[4] = {0.f,0.f,0.f,0.f}, s1[4] = {0.f,0.f,0.f,0.f};
    float q0[4] = {0.f,0.f,0.f,0.f}, q1[4] = {0.f,0.f,0.f,0.f};
    float mn[4] = {INFINITY, INFINITY, INFINITY, INFINITY};
    float mx[4] = {-INFINITY, -INFINITY, -INFINITY, -INFINITY};

    int bidx = 0;              // graph (row) index within this wave's 4
    int seg_start = wave_start;
    int next_b = __shfl(ob, 1);

    char* lbase = (char*)As;
    // flush: finalize graph bidx with rows [seg_start, bend) and write its
    // bf16 LDS row; reset accumulators; advance boundary bookkeeping.
    auto flush = [&]() {
        const int bend = __shfl(ob, bidx + 1);
        const int cnt = bend - seg_start;
        const float cf = (float)cnt;
        const float inv = cnt > 0 ? 1.f / cf : 0.f;
        const float invm1 = 1.f / fmaxf(cf - 1.f, 1.f);
        float mean[4], sd[4];
#pragma unroll
        for (int i = 0; i < 4; ++i) {
            float s = s0[i] + s1[i];
            float q = q0[i] + q1[i];
            mean[i] = s * inv;                           // 0 when empty
            float var = (q - mean[i] * s) * invm1;       // unbiased
            sd[i] = sqrtf(fmaxf(var, 0.f));
            if (cnt == 0) { mn[i] = 0.f; mx[i] = 0.f; }
        }
        const int lr = w * 4 + bidx;
        const unsigned int rx = (unsigned int)((lr & 7) << 4);
        const unsigned int b0 = (unsigned int)(lr * 2048 + lane * 8);
        *(uint2*)(lbase + ((b0 + 0)    ^ rx)) = make_uint2(pack2(mean[0], mean[1]), pack2(mean[2], mean[3]));
        *(uint2*)(lbase + ((b0 + 512)  ^ rx)) = make_uint2(pack2(mn[0], mn[1]),     pack2(mn[2], mn[3]));
        *(uint2*)(lbase + ((b0 + 1024) ^ rx)) = make_uint2(pack2(mx[0], mx[1]),     pack2(mx[2], mx[3]));
        *(uint2*)(lbase + ((b0 + 1536) ^ rx)) = make_uint2(pack2(sd[0], sd[1]),     pack2(sd[2], sd[3]));
#pragma unroll
        for (int i = 0; i < 4; ++i) {
            s0[i] = 0.f; s1[i] = 0.f; q0[i] = 0.f; q1[i] = 0.f;
            mn[i] = INFINITY; mx[i] = -INFINITY;
        }
        seg_start = bend;
        ++bidx;
        next_b = __shfl(ob, bidx < 4 ? bidx + 1 : 4);
    };

    const f32x4* __restrict__ hv = (const f32x4*)h;  // 64 f32x4 per row
    int r = wave_start;
    for (; r + 8 <= wave_end; r += 8) {
        f32x4 v[8];
#pragma unroll
        for (int j = 0; j < 8; ++j)
            v[j] = __builtin_nontemporal_load(hv + (size_t)(r + j) * 64 + lane);
#pragma unroll
        for (int j = 0; j < 8; ++j) {
            while (r + j == next_b && bidx < 3) flush();  // uniform, rare
            if (j & 1) {
#pragma unroll
                for (int i = 0; i < 4; ++i) {
                    s1[i] += v[j][i]; q1[i] = fmaf(v[j][i], v[j][i], q1[i]);
                    mn[i] = fminf(mn[i], v[j][i]); mx[i] = fmaxf(mx[i], v[j][i]);
                }
            } else {
#pragma unroll
                for (int i = 0; i < 4; ++i) {
                    s0[i] += v[j][i]; q0[i] = fmaf(v[j][i], v[j][i], q0[i]);
                    mn[i] = fminf(mn[i], v[j][i]); mx[i] = fmaxf(mx[i], v[j][i]);
                }
            }
        }
    }
    for (; r < wave_end; ++r) {
        f32x4 a = __builtin_nontemporal_load(hv + (size_t)r * 64 + lane);
        while (r == next_b && bidx < 3) flush();
#pragma unroll
        for (int i = 0; i < 4; ++i) {
            s0[i] += a[i]; q0[i] = fmaf(a[i], a[i], q0[i]);
            mn[i] = fminf(mn[i], a[i]); mx[i] = fmaxf(mx[i], a[i]);
        }
    }
    while (bidx < 4) flush();  // last graph + trailing empty graphs

    __syncthreads();

    // ---- GEMM: rows [0,16) x cols [64w..+64) ----
    const int fr = lane & 15;   // A row / B col within frag
    const int gq = lane >> 4;   // k octet within 32-k step
    const unsigned int arx = (unsigned int)((fr & 7) << 4);
    const unsigned int abase = (unsigned int)(fr * 2048 + gq * 16);

    f32x4 acc[4] = {{0.f,0.f,0.f,0.f},{0.f,0.f,0.f,0.f},{0.f,0.f,0.f,0.f},{0.f,0.f,0.f,0.f}};

    const unsigned short* Bb[4];
#pragma unroll
    for (int fc = 0; fc < 4; ++fc)
        Bb[fc] = BT + ((((size_t)(w * 4 + fc) * 128 + gq) * 16 + fr) << 3);

#pragma unroll 2
    for (int t = 0; t < 32; ++t) {
        bf16x8 af = *(const bf16x8*)((const char*)As + ((abase + t * 64) ^ arx));
#pragma unroll
        for (int fc = 0; fc < 4; ++fc) {
            bf16x8 bfr = *(const bf16x8*)(Bb[fc] + t * 512);
            acc[fc] = __builtin_amdgcn_mfma_f32_16x16x32_bf16(af, bfr, acc[fc], 0, 0, 0);
        }
    }

    const size_t row0 = (size_t)tile * 16;
#pragma unroll
    for (int fc = 0; fc < 4; ++fc) {
        int col = w * 64 + fc * 16 + fr;
        float bv = bias[col];
#pragma unroll
        for (int e = 0; e < 4; ++e) {
            size_t row = row0 + gq * 4 + e;
            out[row * NOUT + col] = acc[fc][e] + bv;
        }
    }
}

extern "C" void kernel_launch(void* const* d_in, const int* in_sizes, int n_in,
                              void* d_out, int out_size, void* d_ws, size_t ws_size,
                              hipStream_t stream) {
    const float* h     = (const float*)d_in[0];
    const int*   batch = (const int*)d_in[1];
    const float* W     = (const float*)d_in[2];
    const float* b     = (const float*)d_in[3];
    float* out = (float*)d_out;

    const int N = in_sizes[0] / DIM;  // 500000 (unambiguous regardless of batch dtype)

    // workspace layout
    char* ws = (char*)d_ws;
    unsigned short* WT = (unsigned short*)ws;      // B': 256*1024 bf16 = 512 KB
    int* offs = (int*)(ws + 524288);               // 8193 ints

    prep_kernel<<<97, 256, 0, stream>>>(W, batch, N, WT, offs);
    fused_kernel<<<NG / 16, 256, 0, stream>>>(h, offs, WT, b, out);
}